// Round 5
// baseline (1509.184 us; speedup 1.0000x reference)
//
#include <hip/hip_runtime.h>
#include <math.h>
#include <stdint.h>

#define C_ 8
#define K_ 64
#define D_ 32
#define N_ 2048

// ---- packed per-(c,k) weight chunk (floats), CH floats each ----
#define CH   4352  // 4320 used + 32 pad
#define OW1S 0     // W1s packed [64][16]  (used input cols only)
#define OW2S 1024  // W2s packed [16][64]  (updated output rows only)
#define OW1T 2048
#define OW2T 3072
#define OB1S 4096  // [64]
#define OB1T 4160  // [64]
#define OB2S 4224  // [16] packed (updated rows)
#define OB2T 4240  // [16]
#define OAT  4256  // at_even[16], at_odd[16]
#define OEA  4288  // ea_even[16], ea_odd[16]

// ws layout (floats): els[256] @0, CONST[8] @256, logp @512, Bn @16896, A @33280

// ---------------- packing ----------------
__global__ __launch_bounds__(256) void k_pack(
    const float* __restrict__ sW1, const float* __restrict__ sb1,
    const float* __restrict__ sW2, const float* __restrict__ sb2,
    const float* __restrict__ tW1, const float* __restrict__ tb1,
    const float* __restrict__ tW2, const float* __restrict__ tb2,
    const float* __restrict__ an_s, const float* __restrict__ an_t,
    float* __restrict__ pk) {
  const int b = blockIdx.x;  // = c*64 + k
  const int k = b & 63, pin = k & 1;
  const int ck = b;
  float* dst = pk + (size_t)b * CH;
  const int t = threadIdx.x;
  {  // W1 gather: j = t>>2 in [0,64), quad q
    const int j = t >> 2, q = (t & 3) << 2;
    const float* s1 = sW1 + ck * 2048 + j * 32 + pin;
    const float* t1 = tW1 + ck * 2048 + j * 32 + pin;
    float4 vs = make_float4(s1[2 * q], s1[2 * q + 2], s1[2 * q + 4], s1[2 * q + 6]);
    float4 vt = make_float4(t1[2 * q], t1[2 * q + 2], t1[2 * q + 4], t1[2 * q + 6]);
    *(float4*)(dst + OW1S + j * 16 + q) = vs;
    *(float4*)(dst + OW1T + j * 16 + q) = vt;
  }
  {  // W2 gather: o = t>>4 in [0,16), jq
    const int o = t >> 4, jq = (t & 15) << 2;
    const int row = 2 * o + 1 - pin;
    const float4 vs = *(const float4*)(sW2 + ck * 2048 + row * 64 + jq);
    const float4 vt = *(const float4*)(tW2 + ck * 2048 + row * 64 + jq);
    *(float4*)(dst + OW2S + o * 64 + jq) = vs;
    *(float4*)(dst + OW2T + o * 64 + jq) = vt;
  }
  if (t < 64) {
    dst[OB1S + t] = sb1[ck * 64 + t];
    dst[OB1T + t] = tb1[ck * 64 + t];
  } else if (t < 80) {
    const int o = t - 64;
    dst[OB2S + o] = sb2[ck * 32 + 2 * o + 1 - pin];
    dst[OB2T + o] = tb2[ck * 32 + 2 * o + 1 - pin];
  } else if (t < 96) {
    const int i = t - 80;
    dst[OAT + i] = an_t[ck * 32 + 2 * i];
    dst[OAT + 16 + i] = an_t[ck * 32 + 2 * i + 1];
    dst[OEA + i] = expf(-an_s[ck * 32 + 2 * i]);
    dst[OEA + 16 + i] = expf(-an_s[ck * 32 + 2 * i + 1]);
  }
}

__global__ __launch_bounds__(256) void k_pre(const float* __restrict__ log_scale,
                                             float* __restrict__ ws) {
  int g = threadIdx.x;
  if (g < C_ * D_) ws[g] = expf(-log_scale[g]);
}

__global__ __launch_bounds__(512) void k_const(const float* __restrict__ an_s,
                                               const float* __restrict__ log_scale,
                                               float* __restrict__ ws) {
  int tid = threadIdx.x;
  int c = tid >> 6, lane = tid & 63;
  float acc = 0.f;
  for (int r = 0; r < 32; ++r) acc += an_s[c * 2048 + r * 64 + lane];
  if (lane < 32) acc += log_scale[c * 32 + lane];
  for (int off = 32; off; off >>= 1) acc += __shfl_down(acc, off);
  if (lane == 0) ws[256 + c] = -acc - 29.406033062549525f;  // 0.5*32*log(2pi)
}

// ---------------- flow layer pieces ----------------
// fwd: actnorm both parities, two MLPs using x, write GEMM2 partials to ex.
// wb points at the GLOBAL packed chunk; every index is wave-uniform
// (c/k/jb/compile-time), so these loads scalarize to s_load from the
// XCD-L2-resident chunk and the FMAs consume SGPR operands directly.
template <int PIN>
__device__ __forceinline__ void layer_fwd(const float* __restrict__ wb,
                                          float* ex, int w, int idx0,
                                          float (&x)[16], float (&y)[16]) {
  const float* at_x = wb + OAT + 16 * PIN;
  const float* at_y = wb + OAT + 16 * (1 - PIN);
  const float* ea_x = wb + OEA + 16 * PIN;
  const float* ea_y = wb + OEA + 16 * (1 - PIN);
#pragma unroll
  for (int i = 0; i < 16; ++i) {
    x[i] = (x[i] - at_x[i]) * ea_x[i];
    y[i] = (y[i] - at_y[i]) * ea_y[i];
  }

  const int jb = w * 16;
  const int basew = idx0 ^ (w * 16);
  float h[16], p[16];

  // ---- s MLP ----
#pragma unroll
  for (int jj = 0; jj < 16; ++jj) {
    const float* wr = wb + OW1S + (jb + jj) * 16;
    float acc = wb[OB1S + jb + jj];
#pragma unroll
    for (int i = 0; i < 16; ++i) acc = fmaf(wr[i], x[i], acc);
    h[jj] = fmaxf(acc, 0.f);
  }
#pragma unroll
  for (int o = 0; o < 16; ++o) {
    const float* wr = wb + OW2S + o * 64 + jb;
    float acc = (w == 0) ? wb[OB2S + o] : 0.f;
#pragma unroll
    for (int jj = 0; jj < 16; ++jj) acc = fmaf(wr[jj], h[jj], acc);
    p[o] = acc;
  }
#pragma unroll
  for (int q = 0; q < 4; ++q)
    *(float4*)(ex + (basew ^ (q * 4))) =
        make_float4(p[4 * q], p[4 * q + 1], p[4 * q + 2], p[4 * q + 3]);

  // ---- t MLP ----
#pragma unroll
  for (int jj = 0; jj < 16; ++jj) {
    const float* wr = wb + OW1T + (jb + jj) * 16;
    float acc = wb[OB1T + jb + jj];
#pragma unroll
    for (int i = 0; i < 16; ++i) acc = fmaf(wr[i], x[i], acc);
    h[jj] = fmaxf(acc, 0.f);
  }
#pragma unroll
  for (int o = 0; o < 16; ++o) {
    const float* wr = wb + OW2T + o * 64 + jb;
    float acc = (w == 0) ? wb[OB2T + o] : 0.f;
#pragma unroll
    for (int jj = 0; jj < 16; ++jj) acc = fmaf(wr[jj], h[jj], acc);
    p[o] = acc;
  }
#pragma unroll
  for (int q = 0; q < 4; ++q)
    *(float4*)(ex + 4096 + (basew ^ (q * 4))) =
        make_float4(p[4 * q], p[4 * q + 1], p[4 * q + 2], p[4 * q + 3]);
}

// fin: reduce 4-wave partials from ex, apply affine update to y, accumulate ld.
__device__ __forceinline__ void layer_fin(const float* ex, int idx0,
                                          float (&y)[16], float& ld) {
  float sv[16], tv[16];
#pragma unroll
  for (int g = 0; g < 16; ++g) {
    float4 v = *(const float4*)(ex + (idx0 ^ (g * 4)));
    const int ob = (g & 3) * 4;
    if (g < 4) { sv[ob] = v.x; sv[ob + 1] = v.y; sv[ob + 2] = v.z; sv[ob + 3] = v.w; }
    else       { sv[ob] += v.x; sv[ob + 1] += v.y; sv[ob + 2] += v.z; sv[ob + 3] += v.w; }
  }
#pragma unroll
  for (int g = 0; g < 16; ++g) {
    float4 v = *(const float4*)(ex + 4096 + (idx0 ^ (g * 4)));
    const int ob = (g & 3) * 4;
    if (g < 4) { tv[ob] = v.x; tv[ob + 1] = v.y; tv[ob + 2] = v.z; tv[ob + 3] = v.w; }
    else       { tv[ob] += v.x; tv[ob + 1] += v.y; tv[ob + 2] += v.z; tv[ob + 3] += v.w; }
  }
#pragma unroll
  for (int o = 0; o < 16; ++o) {
    y[o] = (y[o] - tv[o]) * __expf(-sv[o]);
    ld -= sv[o];
  }
}

__global__ __launch_bounds__(256, 1) void k_flow(
    const float* __restrict__ nodes, const float* __restrict__ pk,
    const float* __restrict__ loc, const float* __restrict__ ws,
    float* __restrict__ logp) {
  __shared__ float ex[8192];   // exchange buffer: s @0, t @4096 (32 KB)

  const int lane = threadIdx.x;
  const int w = __builtin_amdgcn_readfirstlane((int)threadIdx.y);
  const int c = blockIdx.x & 7;        // component -> XCD (chunk L2-resident)
  const int grp = blockIdx.x >> 3;
  const int node = grp * 64 + lane;

  float ze[16], zo[16];
  {
    const float4* np = (const float4*)(nodes + node * D_);
#pragma unroll
    for (int q = 0; q < 8; ++q) {
      float4 v = np[q];
      ze[2 * q] = v.x; zo[2 * q] = v.y; ze[2 * q + 1] = v.z; zo[2 * q + 1] = v.w;
    }
  }
  const int swzf = ((lane & 15) ^ (((lane >> 4) & 1) << 2)) * 4;
  const int idx0 = lane * 64 + swzf;
  float ld = 0.f;

  const float* __restrict__ chunks = pk + (size_t)c * (K_ * CH);

#pragma unroll 1
  for (int k = 63; k > 0; k -= 2) {
    // ---------- layer k (PIN=1): x=zo kept, y=ze updated ----------
    layer_fwd<1>(chunks + k * CH, ex, w, idx0, zo, ze);
    __syncthreads();                 // partials visible
    layer_fin(ex, idx0, ze, ld);
    __syncthreads();                 // ex reads done

    // ---------- layer k-1 (PIN=0): x=ze kept, y=zo updated ----------
    layer_fwd<0>(chunks + (k - 1) * CH, ex, w, idx0, ze, zo);
    __syncthreads();
    layer_fin(ex, idx0, zo, ld);
    __syncthreads();
  }

  if (w == 0) {
    const float* lc = loc + c * D_;
    const float* el = ws + c * D_;
    float sq = 0.f;
#pragma unroll
    for (int i = 0; i < 16; ++i) {
      float a = (ze[i] - lc[2 * i]) * el[2 * i];
      float b = (zo[i] - lc[2 * i + 1]) * el[2 * i + 1];
      sq += a * a + b * b;
    }
    logp[c * N_ + node] = ld + ws[256 + c] - 0.5f * sq;
  }
}

// ---------------- tail kernels ----------------
__global__ __launch_bounds__(256) void k_norm(const float* __restrict__ logp,
                                              float* __restrict__ Bn) {
  __shared__ float red[256];
  const int c = blockIdx.x;
  const int t = threadIdx.x;
  float e[8];
  float part = 0.f;
#pragma unroll
  for (int r = 0; r < 8; ++r) {
    e[r] = __expf(logp[c * N_ + r * 256 + t]);
    part += e[r];
  }
  red[t] = part;
  __syncthreads();
  for (int s = 128; s > 0; s >>= 1) {
    if (t < s) red[t] += red[t + s];
    __syncthreads();
  }
  const float inv = 1.f / fmaxf(red[0], 1e-12f);  // literal clamp, NO max-shift
#pragma unroll
  for (int r = 0; r < 8; ++r) Bn[c * N_ + r * 256 + t] = e[r] * inv;
}

__global__ __launch_bounds__(256) void k_A(const float* __restrict__ S_unc,
                                           const float* __restrict__ Bn,
                                           float* __restrict__ A) {
  __shared__ float sE[64];
  __shared__ float sInv;
  const int t = threadIdx.x;
  if (t < 64) sE[t] = __expf(S_unc[t]);
  __syncthreads();
  if (t == 0) {
    float tot = 0.f;
    for (int i = 0; i < 64; ++i) tot += sE[i];
    sInv = 1.f / tot;
  }
  __syncthreads();
  const int j = blockIdx.x * 256 + t;
  float b[8];
#pragma unroll
  for (int cc = 0; cc < 8; ++cc) b[cc] = Bn[cc * N_ + j];
#pragma unroll
  for (int c = 0; c < 8; ++c) {
    float acc = 0.f;
#pragma unroll
    for (int cc = 0; cc < 8; ++cc) acc += sE[c * 8 + cc] * b[cc];
    A[c * N_ + j] = acc * sInv;
  }
}

__global__ __launch_bounds__(256) void k_out(const float* __restrict__ Bn,
                                             const float* __restrict__ A,
                                             float* __restrict__ out) {
  const int T = blockIdx.x * 256 + threadIdx.x;
  const int i0 = (T >> 9) << 2;
  const int j0 = (T & 511) << 2;
  float acc[4][4];
#pragma unroll
  for (int r = 0; r < 4; ++r)
#pragma unroll
    for (int e2 = 0; e2 < 4; ++e2) acc[r][e2] = 0.f;
#pragma unroll
  for (int cc = 0; cc < 8; ++cc) {
    const float4 bi = *(const float4*)(Bn + cc * N_ + i0);
    const float4 aj = *(const float4*)(A + cc * N_ + j0);
    const float br[4] = {bi.x, bi.y, bi.z, bi.w};
    const float ar[4] = {aj.x, aj.y, aj.z, aj.w};
#pragma unroll
    for (int r = 0; r < 4; ++r)
#pragma unroll
      for (int e2 = 0; e2 < 4; ++e2) acc[r][e2] += br[r] * ar[e2];
  }
#pragma unroll
  for (int r = 0; r < 4; ++r)
    *(float4*)(out + (i0 + r) * N_ + j0) =
        make_float4(acc[r][0], acc[r][1], acc[r][2], acc[r][3]);
}

extern "C" void kernel_launch(void* const* d_in, const int* in_sizes, int n_in,
                              void* d_out, int out_size, void* d_ws,
                              size_t ws_size, hipStream_t stream) {
  const float* nodes = (const float*)d_in[0];
  const float* sW1 = (const float*)d_in[1];
  const float* sb1 = (const float*)d_in[2];
  const float* sW2 = (const float*)d_in[3];
  const float* sb2 = (const float*)d_in[4];
  const float* tW1 = (const float*)d_in[5];
  const float* tb1 = (const float*)d_in[6];
  const float* tW2 = (const float*)d_in[7];
  const float* tb2 = (const float*)d_in[8];
  const float* an_s = (const float*)d_in[9];
  const float* an_t = (const float*)d_in[10];
  const float* loc = (const float*)d_in[11];
  const float* log_scale = (const float*)d_in[12];
  const float* S_unc = (const float*)d_in[13];
  float* out = (float*)d_out;
  float* ws = (float*)d_ws;

  // packed weights live in d_out (8.9 MB of 16.8 MB); overwritten by k_out last
  float* pkw = out;
  float* logp = ws + 512;
  float* Bn = ws + 16896;
  float* A = ws + 33280;

  k_pack<<<512, 256, 0, stream>>>(sW1, sb1, sW2, sb2, tW1, tb1, tW2, tb2,
                                  an_s, an_t, pkw);
  k_pre<<<1, 256, 0, stream>>>(log_scale, ws);
  k_const<<<1, 512, 0, stream>>>(an_s, log_scale, ws);

  k_flow<<<256, dim3(64, 4), 0, stream>>>(nodes, pkw, loc, ws, logp);

  k_norm<<<8, 256, 0, stream>>>(logp, Bn);
  k_A<<<8, 256, 0, stream>>>(S_unc, Bn, A);
  k_out<<<1024, 256, 0, stream>>>(Bn, A, out);
}

// Round 6
// 197.276 us; speedup vs baseline: 7.6501x; 7.6501x over previous
//
#include <hip/hip_runtime.h>
#include <math.h>
#include <stdint.h>

#define C_ 8
#define K_ 64
#define D_ 32
#define N_ 2048

typedef _Float16 f16x4 __attribute__((ext_vector_type(4)));
typedef float    f32x4 __attribute__((ext_vector_type(4)));

// ---- per-(c,k) packed blob: 2304 floats (9216 B) ----
//  [0,2048) floats: 16 MFMA A-frag tiles, each [64 lanes][4 f16] (512 B)
//    t0-3:  GEMM1-s  A=W1s (rows=hid 16t.., cols=masked-in, lane: row=l&15, k=4*(l>>4)+a)
//    t4-7:  GEMM2-s  A=W2s (rows=packed-out, cols=hid 16(t-4)..)
//    t8-11: GEMM1-t,  t12-15: GEMM2-t
//  [2048,2176): b1 frags [mlp][t][g][r] f32
//  [2176,2208): b2 frags [mlp][g][r] f32
//  [2208,2272): an frags [g][16] f32: {at_e[4], ea_e[4], at_o[4], ea_o[4]}
//  [2272,2304): pad
#define BLOBF 2304
#define BLOBB (BLOBF * 4)
#define OB1   2048
#define OB2   2176
#define OAN   2208

// ws layout (floats): locels [c][g][16] @0 (512), CONST[8] @512,
//                     logp @520, Bn @16904, A @33288

__device__ __forceinline__ f16x4 ldfrag(const char* p) {
  union { uint2 u; f16x4 h; } cv;
  cv.u = *(const uint2*)p;
  return cv.h;
}

// ---------------- packing ----------------
__global__ __launch_bounds__(64) void k_pack(
    const float* __restrict__ sW1, const float* __restrict__ sb1,
    const float* __restrict__ sW2, const float* __restrict__ sb2,
    const float* __restrict__ tW1, const float* __restrict__ tb1,
    const float* __restrict__ tW2, const float* __restrict__ tb2,
    const float* __restrict__ an_s, const float* __restrict__ an_t,
    float* __restrict__ pk) {
  const int b = blockIdx.x;        // = c*64 + k
  const int pin = b & 1;
  const int l = threadIdx.x;
  const int g = l >> 4, m15 = l & 15;
  float* dst = pk + (size_t)b * BLOBF;
  char* dstc = (char*)dst;

#pragma unroll
  for (int t = 0; t < 16; ++t) {
    const int mlp = t >> 3, tt = t & 7;
    const float* W1 = mlp ? tW1 : sW1;
    const float* W2 = mlp ? tW2 : sW2;
    union { uint2 u; f16x4 h; } cv;
    if (tt < 4) {  // GEMM1: A[row=hid=16tt+m15][k=packed-in=4g+a] = W1[hid][2k+pin]
      const float* row = W1 + b * 2048 + (16 * tt + m15) * 32;
#pragma unroll
      for (int a = 0; a < 4; ++a) cv.h[a] = (_Float16)row[2 * (4 * g + a) + pin];
    } else {       // GEMM2: A[row=out=m15][k=hid=16(tt-4)+4g+a] = W2[2*out+1-pin][hid]
      const float* row = W2 + b * 2048 + (2 * m15 + 1 - pin) * 64;
#pragma unroll
      for (int a = 0; a < 4; ++a) cv.h[a] = (_Float16)row[16 * (tt - 4) + 4 * g + a];
    }
    *(uint2*)(dstc + t * 512 + l * 8) = cv.u;
  }
  // b1 frags: C1 init value for (mlp, tile t, lane-group g, reg r) = b1[16t+4g+r]
#pragma unroll
  for (int i = l; i < 128; i += 64) {
    const int mlp = i >> 6, t = (i >> 4) & 3, gg = (i >> 2) & 3, r = i & 3;
    dst[OB1 + i] = (mlp ? tb1 : sb1)[b * 64 + 16 * t + 4 * gg + r];
  }
  // b2 frags: C2 init for (mlp, g, r) = b2[2*(4g+r)+1-pin]
  if (l < 32) {
    const int mlp = l >> 4, gg = (l >> 2) & 3, r = l & 3;
    dst[OB2 + l] = (mlp ? tb2 : sb2)[b * 32 + 2 * (4 * gg + r) + 1 - pin];
  }
  // an frags [g][16]: slots {at_e, ea_e, at_o, ea_o} x4, dim = 2*(4g+j)+par
  {
    const int gg = l >> 4, slot = l & 15, j = slot & 3;
    const int par = slot >> 3, isEa = (slot >> 2) & 1;
    const int dim = 2 * (4 * gg + j) + par;
    dst[OAN + l] = isEa ? expf(-an_s[b * 32 + dim]) : an_t[b * 32 + dim];
  }
}

// locels frags: ws[c][g][16] = {loc_e, els_e, loc_o, els_o}
__global__ __launch_bounds__(512) void k_pre(const float* __restrict__ loc,
                                             const float* __restrict__ log_scale,
                                             float* __restrict__ ws) {
  const int i = threadIdx.x;
  const int c = i >> 6, gg = (i >> 4) & 3, slot = i & 15, j = slot & 3;
  const int par = slot >> 3, isE = (slot >> 2) & 1;
  const int dim = 2 * (4 * gg + j) + par;
  ws[i] = isE ? expf(-log_scale[c * 32 + dim]) : loc[c * 32 + dim];
}

__global__ __launch_bounds__(512) void k_const(const float* __restrict__ an_s,
                                               const float* __restrict__ log_scale,
                                               float* __restrict__ ws) {
  int tid = threadIdx.x;
  int c = tid >> 6, lane = tid & 63;
  float acc = 0.f;
  for (int r = 0; r < 32; ++r) acc += an_s[c * 2048 + r * 64 + lane];
  if (lane < 32) acc += log_scale[c * 32 + lane];
  for (int off = 32; off; off >>= 1) acc += __shfl_down(acc, off);
  if (lane == 0) ws[512 + c] = -acc - 29.406033062549525f;  // 0.5*32*log(2pi)
}

// ---------------- one flow layer, pure in-wave MFMA ----------------
// x = kept parity (PIN), y = updated parity; both are this lane's packed dims
// 4g..4g+3 of node (l&15). GEMM1 C (row=hid local, col=node) feeds GEMM2 B
// (k=hid local, col=node) at the SAME lane (j=r) -> in-lane relu+cvt only.
template <int PIN>
__device__ __forceinline__ void layer_mfma(const char* bp, int g, int fo,
                                           float (&x)[4], float (&y)[4],
                                           float& ldp) {
  const float* bf = (const float*)bp;
  const f32x4 ane = *(const f32x4*)(bf + OAN + g * 16 + 0);
  const f32x4 aee = *(const f32x4*)(bf + OAN + g * 16 + 4);
  const f32x4 ano = *(const f32x4*)(bf + OAN + g * 16 + 8);
  const f32x4 aeo = *(const f32x4*)(bf + OAN + g * 16 + 12);
  const f32x4 atx = PIN ? ano : ane, eax = PIN ? aeo : aee;
  const f32x4 aty = PIN ? ane : ano, eay = PIN ? aee : aeo;
  f16x4 bx;
#pragma unroll
  for (int j = 0; j < 4; ++j) {
    x[j] = (x[j] - atx[j]) * eax[j];
    y[j] = (y[j] - aty[j]) * eay[j];
    bx[j] = (_Float16)x[j];
  }
  f32x4 c2s = *(const f32x4*)(bf + OB2 + g * 4);
  f32x4 c2t = *(const f32x4*)(bf + OB2 + 16 + g * 4);
  // s-MLP: 4x (GEMM1 tile -> relu/cvt -> GEMM2 accumulate)
#pragma unroll
  for (int t = 0; t < 4; ++t) {
    f32x4 c1 = *(const f32x4*)(bf + OB1 + (t * 4 + g) * 4);
    c1 = __builtin_amdgcn_mfma_f32_16x16x16f16(ldfrag(bp + t * 512 + fo), bx, c1, 0, 0, 0);
    f16x4 bh;
#pragma unroll
    for (int j = 0; j < 4; ++j) bh[j] = (_Float16)fmaxf(c1[j], 0.f);
    c2s = __builtin_amdgcn_mfma_f32_16x16x16f16(ldfrag(bp + (4 + t) * 512 + fo), bh, c2s, 0, 0, 0);
  }
  // t-MLP
#pragma unroll
  for (int t = 0; t < 4; ++t) {
    f32x4 c1 = *(const f32x4*)(bf + OB1 + 64 + (t * 4 + g) * 4);
    c1 = __builtin_amdgcn_mfma_f32_16x16x16f16(ldfrag(bp + (8 + t) * 512 + fo), bx, c1, 0, 0, 0);
    f16x4 bh;
#pragma unroll
    for (int j = 0; j < 4; ++j) bh[j] = (_Float16)fmaxf(c1[j], 0.f);
    c2t = __builtin_amdgcn_mfma_f32_16x16x16f16(ldfrag(bp + (12 + t) * 512 + fo), bh, c2t, 0, 0, 0);
  }
#pragma unroll
  for (int r = 0; r < 4; ++r) {
    const float sv = c2s[r];
    y[r] = (y[r] - c2t[r]) * __expf(-sv);
    ldp -= sv;
  }
}

__global__ __launch_bounds__(256) void k_flow(
    const float* __restrict__ nodes, const float* __restrict__ pk,
    const float* __restrict__ ws, float* __restrict__ logp) {
  const int l = threadIdx.x & 63;
  const int wv = threadIdx.x >> 6;
  const int g = l >> 4, m15 = l & 15;
  const int fo = l * 8;
  const int c = blockIdx.x & 7;                    // component -> XCD L2 pin
  const int nb = (blockIdx.x >> 3) * 64 + wv * 16; // wave's node base
  const int node = nb + m15;

  // lane holds dims [8g, 8g+8) of its node: even-packed xe[4], odd-packed xo[4]
  float xe[4], xo[4];
  {
    const float4 v0 = *(const float4*)(nodes + node * 32 + 8 * g);
    const float4 v1 = *(const float4*)(nodes + node * 32 + 8 * g + 4);
    xe[0] = v0.x; xo[0] = v0.y; xe[1] = v0.z; xo[1] = v0.w;
    xe[2] = v1.x; xo[2] = v1.y; xe[3] = v1.z; xo[3] = v1.w;
  }
  float ldp = 0.f;
  const char* bp0 = (const char*)pk + (size_t)(c * 64) * BLOBB;

#pragma unroll 1
  for (int k = 63; k > 0; k -= 2) {
    layer_mfma<1>(bp0 + (size_t)k * BLOBB, g, fo, xo, xe, ldp);
    layer_mfma<0>(bp0 + (size_t)(k - 1) * BLOBB, g, fo, xe, xo, ldp);
  }

  // final DiagGaussian partial over this lane's 8 dims, then group-reduce
  const float* lw = ws + (c * 4 + g) * 16;
  const f32x4 loce = *(const f32x4*)(lw + 0);
  const f32x4 else_ = *(const f32x4*)(lw + 4);
  const f32x4 loco = *(const f32x4*)(lw + 8);
  const f32x4 elso = *(const f32x4*)(lw + 12);
  float sq = 0.f;
#pragma unroll
  for (int j = 0; j < 4; ++j) {
    const float a = (xe[j] - loce[j]) * else_[j];
    const float b2v = (xo[j] - loco[j]) * elso[j];
    sq += a * a + b2v * b2v;
  }
  float part = ldp - 0.5f * sq;
  part += __shfl_xor(part, 16);
  part += __shfl_xor(part, 32);
  if (l < 16) logp[c * N_ + nb + l] = part + ws[512 + c];
}

// ---------------- tail kernels ----------------
__global__ __launch_bounds__(256) void k_norm(const float* __restrict__ logp,
                                              float* __restrict__ Bn) {
  __shared__ float red[256];
  const int c = blockIdx.x;
  const int t = threadIdx.x;
  float e[8];
  float part = 0.f;
#pragma unroll
  for (int r = 0; r < 8; ++r) {
    e[r] = __expf(logp[c * N_ + r * 256 + t]);
    part += e[r];
  }
  red[t] = part;
  __syncthreads();
  for (int s = 128; s > 0; s >>= 1) {
    if (t < s) red[t] += red[t + s];
    __syncthreads();
  }
  const float inv = 1.f / fmaxf(red[0], 1e-12f);  // literal clamp, NO max-shift
#pragma unroll
  for (int r = 0; r < 8; ++r) Bn[c * N_ + r * 256 + t] = e[r] * inv;
}

__global__ __launch_bounds__(256) void k_A(const float* __restrict__ S_unc,
                                           const float* __restrict__ Bn,
                                           float* __restrict__ A) {
  __shared__ float sE[64];
  __shared__ float sInv;
  const int t = threadIdx.x;
  if (t < 64) sE[t] = __expf(S_unc[t]);
  __syncthreads();
  if (t == 0) {
    float tot = 0.f;
    for (int i = 0; i < 64; ++i) tot += sE[i];
    sInv = 1.f / tot;
  }
  __syncthreads();
  const int j = blockIdx.x * 256 + t;
  float b[8];
#pragma unroll
  for (int cc = 0; cc < 8; ++cc) b[cc] = Bn[cc * N_ + j];
#pragma unroll
  for (int c = 0; c < 8; ++c) {
    float acc = 0.f;
#pragma unroll
    for (int cc = 0; cc < 8; ++cc) acc += sE[c * 8 + cc] * b[cc];
    A[c * N_ + j] = acc * sInv;
  }
}

__global__ __launch_bounds__(256) void k_out(const float* __restrict__ Bn,
                                             const float* __restrict__ A,
                                             float* __restrict__ out) {
  const int T = blockIdx.x * 256 + threadIdx.x;
  const int i0 = (T >> 9) << 2;
  const int j0 = (T & 511) << 2;
  float acc[4][4];
#pragma unroll
  for (int r = 0; r < 4; ++r)
#pragma unroll
    for (int e2 = 0; e2 < 4; ++e2) acc[r][e2] = 0.f;
#pragma unroll
  for (int cc = 0; cc < 8; ++cc) {
    const float4 bi = *(const float4*)(Bn + cc * N_ + i0);
    const float4 aj = *(const float4*)(A + cc * N_ + j0);
    const float br[4] = {bi.x, bi.y, bi.z, bi.w};
    const float ar[4] = {aj.x, aj.y, aj.z, aj.w};
#pragma unroll
    for (int r = 0; r < 4; ++r)
#pragma unroll
      for (int e2 = 0; e2 < 4; ++e2) acc[r][e2] += br[r] * ar[e2];
  }
#pragma unroll
  for (int r = 0; r < 4; ++r)
    *(float4*)(out + (i0 + r) * N_ + j0) =
        make_float4(acc[r][0], acc[r][1], acc[r][2], acc[r][3]);
}

extern "C" void kernel_launch(void* const* d_in, const int* in_sizes, int n_in,
                              void* d_out, int out_size, void* d_ws,
                              size_t ws_size, hipStream_t stream) {
  const float* nodes = (const float*)d_in[0];
  const float* sW1 = (const float*)d_in[1];
  const float* sb1 = (const float*)d_in[2];
  const float* sW2 = (const float*)d_in[3];
  const float* sb2 = (const float*)d_in[4];
  const float* tW1 = (const float*)d_in[5];
  const float* tb1 = (const float*)d_in[6];
  const float* tW2 = (const float*)d_in[7];
  const float* tb2 = (const float*)d_in[8];
  const float* an_s = (const float*)d_in[9];
  const float* an_t = (const float*)d_in[10];
  const float* loc = (const float*)d_in[11];
  const float* log_scale = (const float*)d_in[12];
  const float* S_unc = (const float*)d_in[13];
  float* out = (float*)d_out;
  float* ws = (float*)d_ws;

  // packed blobs live in d_out (4.72 MB of 16.8 MB); overwritten by k_out last
  float* pkw = out;
  float* logp = ws + 520;
  float* Bn = ws + 16904;
  float* A = ws + 33288;

  k_pack<<<512, 64, 0, stream>>>(sW1, sb1, sW2, sb2, tW1, tb1, tW2, tb2,
                                 an_s, an_t, pkw);
  k_pre<<<1, 512, 0, stream>>>(loc, log_scale, ws);
  k_const<<<1, 512, 0, stream>>>(an_s, log_scale, ws);

  k_flow<<<256, 256, 0, stream>>>(nodes, pkw, ws, logp);

  k_norm<<<8, 256, 0, stream>>>(logp, Bn);
  k_A<<<8, 256, 0, stream>>>(S_unc, Bn, A);
  k_out<<<1024, 256, 0, stream>>>(Bn, A, out);
}

// Round 7
// 187.277 us; speedup vs baseline: 8.0585x; 1.0534x over previous
//
#include <hip/hip_runtime.h>
#include <math.h>
#include <stdint.h>

#define C_ 8
#define K_ 64
#define D_ 32
#define N_ 2048

typedef _Float16 f16x4 __attribute__((ext_vector_type(4)));
typedef float    f32x4 __attribute__((ext_vector_type(4)));

// ---- per-(c,k) packed blob: 2304 floats (9216 B) ----
//  [0,2048) floats: 16 MFMA A-frag tiles, each [64 lanes][4 f16] (512 B)
//    t0-3:  GEMM1-s  A=W1s (row=l&15=hid16t.., k=4*(l>>4)+a = masked-in)
//    t4-7:  GEMM2-s  A=W2s (row=packed-out, k=hid)
//    t8-11: GEMM1-t,  t12-15: GEMM2-t
//  [2048,2176): b1 frags [mlp][t][g][r] f32
//  [2176,2208): b2 frags [mlp][g][r] f32
//  [2208,2272): an frags [g][16] f32: {at_e[4], ea_e[4], at_o[4], ea_o[4]}
//  [2272,2304): pad
#define BLOBF 2304
#define BLOBB (BLOBF * 4)
#define OB1   2048
#define OB2   2176
#define OAN   2208

// ws layout (floats): locels [c][g][16] @0 (512), CONST[8] @512,
//                     logp @520, Bn @16904, A @33288

__device__ __forceinline__ f16x4 asf16(uint2 u) {
  union { uint2 u; f16x4 h; } cv;
  cv.u = u;
  return cv.h;
}

// ---------------- packing (256 thr: wave w -> tiles 4w..4w+3) ----------------
__global__ __launch_bounds__(256) void k_pack(
    const float* __restrict__ sW1, const float* __restrict__ sb1,
    const float* __restrict__ sW2, const float* __restrict__ sb2,
    const float* __restrict__ tW1, const float* __restrict__ tb1,
    const float* __restrict__ tW2, const float* __restrict__ tb2,
    const float* __restrict__ an_s, const float* __restrict__ an_t,
    float* __restrict__ pk) {
  const int b = blockIdx.x;        // = c*64 + k
  const int pin = b & 1;
  const int tid = threadIdx.x;
  const int wv = tid >> 6, l = tid & 63;
  const int g = l >> 4, m15 = l & 15;
  float* dst = pk + (size_t)b * BLOBF;
  char* dstc = (char*)dst;

#pragma unroll
  for (int ti = 0; ti < 4; ++ti) {
    const int t = wv * 4 + ti;
    const int mlp = t >> 3, tt = t & 7;
    const float* W1 = mlp ? tW1 : sW1;
    const float* W2 = mlp ? tW2 : sW2;
    union { uint2 u; f16x4 h; } cv;
    if (tt < 4) {  // A1[row=16tt+m15][k=4g+a] = W1[row][2k+pin]; vector-read 8 floats
      const float* row = W1 + b * 2048 + (16 * tt + m15) * 32 + 8 * g;
      const float4 u0 = *(const float4*)(row);
      const float4 u1 = *(const float4*)(row + 4);
      if (pin == 0) {
        cv.h[0] = (_Float16)u0.x; cv.h[1] = (_Float16)u0.z;
        cv.h[2] = (_Float16)u1.x; cv.h[3] = (_Float16)u1.z;
      } else {
        cv.h[0] = (_Float16)u0.y; cv.h[1] = (_Float16)u0.w;
        cv.h[2] = (_Float16)u1.y; cv.h[3] = (_Float16)u1.w;
      }
    } else {       // A2[row=m15][k=16(tt-4)+4g+a] = W2[2row+1-pin][k]; contiguous
      const float* row = W2 + b * 2048 + (2 * m15 + 1 - pin) * 64 + 16 * (tt - 4) + 4 * g;
      const float4 v = *(const float4*)row;
      cv.h[0] = (_Float16)v.x; cv.h[1] = (_Float16)v.y;
      cv.h[2] = (_Float16)v.z; cv.h[3] = (_Float16)v.w;
    }
    *(uint2*)(dstc + t * 512 + l * 8) = cv.u;
  }
  if (tid < 128) {
    const int i = tid;
    const int mlp = i >> 6, t = (i >> 4) & 3, gg = (i >> 2) & 3, r = i & 3;
    dst[OB1 + i] = (mlp ? tb1 : sb1)[b * 64 + 16 * t + 4 * gg + r];
  } else if (tid < 160) {
    const int i = tid - 128;
    const int mlp = i >> 4, gg = (i >> 2) & 3, r = i & 3;
    dst[OB2 + i] = (mlp ? tb2 : sb2)[b * 32 + 2 * (4 * gg + r) + 1 - pin];
  } else if (tid < 224) {
    const int i = tid - 160;
    const int gg = i >> 4, slot = i & 15, j = slot & 3;
    const int par = slot >> 3, isEa = (slot >> 2) & 1;
    const int dim = 2 * (4 * gg + j) + par;
    dst[OAN + i] = isEa ? expf(-an_s[b * 32 + dim]) : an_t[b * 32 + dim];
  }
}

// merged k_pre + k_const (one launch)
__global__ __launch_bounds__(512) void k_misc(const float* __restrict__ loc,
                                              const float* __restrict__ log_scale,
                                              const float* __restrict__ an_s,
                                              float* __restrict__ ws) {
  const int i = threadIdx.x;
  {  // locels frags: ws[c][g][16] = {loc_e, els_e, loc_o, els_o}
    const int c = i >> 6, gg = (i >> 4) & 3, slot = i & 15, j = slot & 3;
    const int par = slot >> 3, isE = (slot >> 2) & 1;
    const int dim = 2 * (4 * gg + j) + par;
    ws[i] = isE ? expf(-log_scale[c * 32 + dim]) : loc[c * 32 + dim];
  }
  {  // CONST[c]
    const int c = i >> 6, lane = i & 63;
    float acc = 0.f;
    for (int r = 0; r < 32; ++r) acc += an_s[c * 2048 + r * 64 + lane];
    if (lane < 32) acc += log_scale[c * 32 + lane];
    for (int off = 32; off; off >>= 1) acc += __shfl_down(acc, off);
    if (lane == 0) ws[512 + c] = -acc - 29.406033062549525f;  // 0.5*32*log(2pi)
  }
}

// ---------------- per-layer register blob (double-buffered) ----------------
// All fields compile-time indexed (rule #20): stays in VGPRs (~88/buffer).
struct LR {
  uint2 fr[16];
  f32x4 b1s[4], b1t[4];
  f32x4 b2s, b2t;
  f32x4 ane, aee, ano, aeo;
};

__device__ __forceinline__ void load_layer(const char* __restrict__ bp, int g,
                                           int fo, LR& R) {
#pragma unroll
  for (int t = 0; t < 16; ++t) R.fr[t] = *(const uint2*)(bp + t * 512 + fo);
  const float* bf = (const float*)bp;
#pragma unroll
  for (int t = 0; t < 4; ++t) {
    R.b1s[t] = *(const f32x4*)(bf + OB1 + (t * 4 + g) * 4);
    R.b1t[t] = *(const f32x4*)(bf + OB1 + 64 + (t * 4 + g) * 4);
  }
  R.b2s = *(const f32x4*)(bf + OB2 + g * 4);
  R.b2t = *(const f32x4*)(bf + OB2 + 16 + g * 4);
  R.ane = *(const f32x4*)(bf + OAN + g * 16 + 0);
  R.aee = *(const f32x4*)(bf + OAN + g * 16 + 4);
  R.ano = *(const f32x4*)(bf + OAN + g * 16 + 8);
  R.aeo = *(const f32x4*)(bf + OAN + g * 16 + 12);
}

// one flow layer, pure in-wave MFMA, operands already in registers
template <int PIN>
__device__ __forceinline__ void layer_mfma(const LR& R, float (&x)[4],
                                           float (&y)[4], float& ldp) {
  const f32x4 atx = PIN ? R.ano : R.ane, eax = PIN ? R.aeo : R.aee;
  const f32x4 aty = PIN ? R.ane : R.ano, eay = PIN ? R.aee : R.aeo;
  f16x4 bx;
#pragma unroll
  for (int j = 0; j < 4; ++j) {
    x[j] = (x[j] - atx[j]) * eax[j];
    y[j] = (y[j] - aty[j]) * eay[j];
    bx[j] = (_Float16)x[j];
  }
  f32x4 c2s = R.b2s, c2t = R.b2t;
#pragma unroll
  for (int t = 0; t < 4; ++t) {  // s-MLP
    f32x4 c1 = R.b1s[t];
    c1 = __builtin_amdgcn_mfma_f32_16x16x16f16(asf16(R.fr[t]), bx, c1, 0, 0, 0);
    f16x4 bh;
#pragma unroll
    for (int j = 0; j < 4; ++j) bh[j] = (_Float16)fmaxf(c1[j], 0.f);
    c2s = __builtin_amdgcn_mfma_f32_16x16x16f16(asf16(R.fr[4 + t]), bh, c2s, 0, 0, 0);
  }
#pragma unroll
  for (int t = 0; t < 4; ++t) {  // t-MLP
    f32x4 c1 = R.b1t[t];
    c1 = __builtin_amdgcn_mfma_f32_16x16x16f16(asf16(R.fr[8 + t]), bx, c1, 0, 0, 0);
    f16x4 bh;
#pragma unroll
    for (int j = 0; j < 4; ++j) bh[j] = (_Float16)fmaxf(c1[j], 0.f);
    c2t = __builtin_amdgcn_mfma_f32_16x16x16f16(asf16(R.fr[12 + t]), bh, c2t, 0, 0, 0);
  }
#pragma unroll
  for (int r = 0; r < 4; ++r) {
    const float sv = c2s[r];
    y[r] = (y[r] - c2t[r]) * __expf(-sv);
    ldp -= sv;
  }
}

__global__ __launch_bounds__(256, 1) void k_flow(
    const float* __restrict__ nodes, const float* __restrict__ pk,
    const float* __restrict__ ws, float* __restrict__ logp) {
  const int l = threadIdx.x & 63;
  const int wv = threadIdx.x >> 6;
  const int g = l >> 4, m15 = l & 15;
  const int fo = l * 8;
  const int c = blockIdx.x & 7;                    // component -> XCD L2 pin
  const int nb = (blockIdx.x >> 3) * 64 + wv * 16; // wave's node base
  const int node = nb + m15;

  // lane holds dims [8g, 8g+8) of its node: even-packed xe[4], odd-packed xo[4]
  float xe[4], xo[4];
  {
    const float4 v0 = *(const float4*)(nodes + node * 32 + 8 * g);
    const float4 v1 = *(const float4*)(nodes + node * 32 + 8 * g + 4);
    xe[0] = v0.x; xo[0] = v0.y; xe[1] = v0.z; xo[1] = v0.w;
    xe[2] = v1.x; xo[2] = v1.y; xe[3] = v1.z; xo[3] = v1.w;
  }
  float ldp = 0.f;
  const char* bp0 = (const char*)pk + (size_t)(c * 64) * BLOBB;

  LR RA, RB;
  load_layer(bp0 + (size_t)63 * BLOBB, g, fo, RA);

#pragma unroll 1
  for (int k = 63; k > 0; k -= 2) {
    load_layer(bp0 + (size_t)(k - 1) * BLOBB, g, fo, RB);  // prefetch k-1
    layer_mfma<1>(RA, xo, xe, ldp);                        // compute layer k
    if (k > 1) load_layer(bp0 + (size_t)(k - 2) * BLOBB, g, fo, RA);
    layer_mfma<0>(RB, xe, xo, ldp);                        // compute layer k-1
  }

  // final DiagGaussian partial over this lane's 8 dims, then group-reduce
  const float* lw = ws + (c * 4 + g) * 16;
  const f32x4 loce = *(const f32x4*)(lw + 0);
  const f32x4 else_ = *(const f32x4*)(lw + 4);
  const f32x4 loco = *(const f32x4*)(lw + 8);
  const f32x4 elso = *(const f32x4*)(lw + 12);
  float sq = 0.f;
#pragma unroll
  for (int j = 0; j < 4; ++j) {
    const float a = (xe[j] - loce[j]) * else_[j];
    const float b2v = (xo[j] - loco[j]) * elso[j];
    sq += a * a + b2v * b2v;
  }
  float part = ldp - 0.5f * sq;
  part += __shfl_xor(part, 16);
  part += __shfl_xor(part, 32);
  if (l < 16) logp[c * N_ + nb + l] = part + ws[512 + c];
}

// ---------------- tail kernels ----------------
__global__ __launch_bounds__(256) void k_norm(const float* __restrict__ logp,
                                              float* __restrict__ Bn) {
  __shared__ float red[256];
  const int c = blockIdx.x;
  const int t = threadIdx.x;
  float e[8];
  float part = 0.f;
#pragma unroll
  for (int r = 0; r < 8; ++r) {
    e[r] = __expf(logp[c * N_ + r * 256 + t]);
    part += e[r];
  }
  red[t] = part;
  __syncthreads();
  for (int s = 128; s > 0; s >>= 1) {
    if (t < s) red[t] += red[t + s];
    __syncthreads();
  }
  const float inv = 1.f / fmaxf(red[0], 1e-12f);  // literal clamp, NO max-shift
#pragma unroll
  for (int r = 0; r < 8; ++r) Bn[c * N_ + r * 256 + t] = e[r] * inv;
}

__global__ __launch_bounds__(256) void k_A(const float* __restrict__ S_unc,
                                           const float* __restrict__ Bn,
                                           float* __restrict__ A) {
  __shared__ float sE[64];
  __shared__ float sInv;
  const int t = threadIdx.x;
  if (t < 64) sE[t] = __expf(S_unc[t]);
  __syncthreads();
  if (t == 0) {
    float tot = 0.f;
    for (int i = 0; i < 64; ++i) tot += sE[i];
    sInv = 1.f / tot;
  }
  __syncthreads();
  const int j = blockIdx.x * 256 + t;
  float b[8];
#pragma unroll
  for (int cc = 0; cc < 8; ++cc) b[cc] = Bn[cc * N_ + j];
#pragma unroll
  for (int c = 0; c < 8; ++c) {
    float acc = 0.f;
#pragma unroll
    for (int cc = 0; cc < 8; ++cc) acc += sE[c * 8 + cc] * b[cc];
    A[c * N_ + j] = acc * sInv;
  }
}

__global__ __launch_bounds__(256) void k_out(const float* __restrict__ Bn,
                                             const float* __restrict__ A,
                                             float* __restrict__ out) {
  const int T = blockIdx.x * 256 + threadIdx.x;
  const int i0 = (T >> 9) << 2;
  const int j0 = (T & 511) << 2;
  float acc[4][4];
#pragma unroll
  for (int r = 0; r < 4; ++r)
#pragma unroll
    for (int e2 = 0; e2 < 4; ++e2) acc[r][e2] = 0.f;
#pragma unroll
  for (int cc = 0; cc < 8; ++cc) {
    const float4 bi = *(const float4*)(Bn + cc * N_ + i0);
    const float4 aj = *(const float4*)(A + cc * N_ + j0);
    const float br[4] = {bi.x, bi.y, bi.z, bi.w};
    const float ar[4] = {aj.x, aj.y, aj.z, aj.w};
#pragma unroll
    for (int r = 0; r < 4; ++r)
#pragma unroll
      for (int e2 = 0; e2 < 4; ++e2) acc[r][e2] += br[r] * ar[e2];
  }
#pragma unroll
  for (int r = 0; r < 4; ++r)
    *(float4*)(out + (i0 + r) * N_ + j0) =
        make_float4(acc[r][0], acc[r][1], acc[r][2], acc[r][3]);
}

extern "C" void kernel_launch(void* const* d_in, const int* in_sizes, int n_in,
                              void* d_out, int out_size, void* d_ws,
                              size_t ws_size, hipStream_t stream) {
  const float* nodes = (const float*)d_in[0];
  const float* sW1 = (const float*)d_in[1];
  const float* sb1 = (const float*)d_in[2];
  const float* sW2 = (const float*)d_in[3];
  const float* sb2 = (const float*)d_in[4];
  const float* tW1 = (const float*)d_in[5];
  const float* tb1 = (const float*)d_in[6];
  const float* tW2 = (const float*)d_in[7];
  const float* tb2 = (const float*)d_in[8];
  const float* an_s = (const float*)d_in[9];
  const float* an_t = (const float*)d_in[10];
  const float* loc = (const float*)d_in[11];
  const float* log_scale = (const float*)d_in[12];
  const float* S_unc = (const float*)d_in[13];
  float* out = (float*)d_out;
  float* ws = (float*)d_ws;

  // packed blobs live in d_out (4.72 MB of 16.8 MB); overwritten by k_out last
  float* pkw = out;
  float* logp = ws + 520;
  float* Bn = ws + 16904;
  float* A = ws + 33288;

  k_pack<<<512, 256, 0, stream>>>(sW1, sb1, sW2, sb2, tW1, tb1, tW2, tb2,
                                  an_s, an_t, pkw);
  k_misc<<<1, 512, 0, stream>>>(loc, log_scale, an_s, ws);

  k_flow<<<256, 256, 0, stream>>>(nodes, pkw, ws, logp);

  k_norm<<<8, 256, 0, stream>>>(logp, Bn);
  k_A<<<8, 256, 0, stream>>>(S_unc, Bn, A);
  k_out<<<1024, 256, 0, stream>>>(Bn, A, out);
}